// Round 1
// baseline (632.370 us; speedup 1.0000x reference)
//
#include <hip/hip_runtime.h>

typedef _Float16 f16;
typedef _Float16 f16x8 __attribute__((ext_vector_type(8)));
typedef float f32x4 __attribute__((ext_vector_type(4)));

#define NB 16
#define NH 256
#define NW 256
#define NC 32
#define NK 5

// LDS x buffer: rows 0..259 (= w+tap), 2 zero-pad rows each side.
// Row stride 40 f16 = 80 B = 20 banks -> only 2-way bank aliasing (free).
#define XP_STRIDE 40
#define XP_ROWS 260

__global__ __launch_bounds__(1024, 1)
void mvcnn_down(const float* __restrict__ in, const float* __restrict__ wt,
                const float* __restrict__ bias, float* __restrict__ out) {
  __shared__ __align__(16) f16 xpad[XP_ROWS * XP_STRIDE];  // 20800 B
  __shared__ __align__(16) f16 rbuf[NW * NC];              // 16384 B, r_{h-1}

  const int b    = blockIdx.x;
  const int t    = threadIdx.x;
  const int lane = t & 63;
  const int wv   = t >> 6;      // wave id == m-tile (w0 = 16*wv)
  const int n16  = lane & 15;
  const int q    = lane >> 4;   // quad 0..3

  // ---- preload weight B-fragments (resident all kernel) ----
  // B[k][n] for k-slice tap: B[c][o] = wt[(c*NK+tap)*NC + o]
  // lane holds k = q*8+j, n = n16;  o = nt*16 + n16
  f16x8 bfrag[NK][2];
  #pragma unroll
  for (int tap = 0; tap < NK; ++tap) {
    #pragma unroll
    for (int nt = 0; nt < 2; ++nt) {
      f16x8 f;
      #pragma unroll
      for (int j = 0; j < 8; ++j) {
        int c = q * 8 + j;
        int o = nt * 16 + n16;
        f[j] = (f16)wt[(c * NK + tap) * NC + o];
      }
      bfrag[tap][nt] = f;
    }
  }
  const float bias0 = bias[n16];
  const float bias1 = bias[16 + n16];

  // zero LDS (pad rows of xpad stay zero forever; rbuf = r_{-1} = 0)
  for (int i = t; i < XP_ROWS * XP_STRIDE; i += 1024) xpad[i] = (f16)0.f;
  for (int i = t; i < NW * NC; i += 1024) rbuf[i] = (f16)0.f;
  __syncthreads();

  const float* inb  = in  + (size_t)b * NH * NW * NC;
  float*       outb = out + (size_t)b * NH * NW * NC;

  // staging map: thread t -> w = t>>2, channels c8..c8+7
  const int wS   = t >> 2;
  const int c8   = (t & 3) * 8;
  const int sidx = wS * NC + c8;   // flat [w][c] offset (NC==32)

  // preload input row 0
  float4 A0 = *(const float4*)(inb + sidx);
  float4 A1 = *(const float4*)(inb + sidx + 4);

  const int arow = wv * 16 + n16;  // A-operand row m = lane&15 within tile

  for (int h = 0; h < NH; ++h) {
    // ---- stage: x = in_h + r_{h-1} -> f16 xpad ----
    f16x8 rv = *(const f16x8*)(&rbuf[sidx]);
    f16x8 xv;
    xv[0] = (f16)(A0.x + (float)rv[0]);
    xv[1] = (f16)(A0.y + (float)rv[1]);
    xv[2] = (f16)(A0.z + (float)rv[2]);
    xv[3] = (f16)(A0.w + (float)rv[3]);
    xv[4] = (f16)(A1.x + (float)rv[4]);
    xv[5] = (f16)(A1.y + (float)rv[5]);
    xv[6] = (f16)(A1.z + (float)rv[6]);
    xv[7] = (f16)(A1.w + (float)rv[7]);
    *(f16x8*)(&xpad[(wS + 2) * XP_STRIDE + c8]) = xv;
    __syncthreads();

    // prefetch next input row (lands during MFMA phase)
    if (h + 1 < NH) {
      const float* nrow = inb + (size_t)(h + 1) * NW * NC;
      A0 = *(const float4*)(nrow + sidx);
      A1 = *(const float4*)(nrow + sidx + 4);
    }

    // ---- MFMA: y[w][o] = sum_{tap,c} xpad[w+tap][c] * B_tap[c][o] ----
    f32x4 acc0 = {0.f, 0.f, 0.f, 0.f};
    f32x4 acc1 = {0.f, 0.f, 0.f, 0.f};
    #pragma unroll
    for (int tap = 0; tap < NK; ++tap) {
      f16x8 af = *(const f16x8*)(&xpad[(arow + tap) * XP_STRIDE + q * 8]);
      acc0 = __builtin_amdgcn_mfma_f32_16x16x32_f16(af, bfrag[tap][0], acc0, 0, 0, 0);
      acc1 = __builtin_amdgcn_mfma_f32_16x16x32_f16(af, bfrag[tap][1], acc1, 0, 0, 0);
    }

    // ---- epilogue: r = relu(y + bias); C/D layout row = q*4+reg, col = n16
    float* orow = outb + (size_t)h * NW * NC;
    #pragma unroll
    for (int reg = 0; reg < 4; ++reg) {
      int wo = wv * 16 + q * 4 + reg;
      float y0 = acc0[reg] + bias0;
      float y1 = acc1[reg] + bias1;
      y0 = y0 > 0.f ? y0 : 0.f;
      y1 = y1 > 0.f ? y1 : 0.f;
      orow[wo * NC + n16]      = y0;
      orow[wo * NC + 16 + n16] = y1;
      rbuf[wo * NC + n16]      = (f16)y0;
      rbuf[wo * NC + 16 + n16] = (f16)y1;
    }
    __syncthreads();
  }
}

extern "C" void kernel_launch(void* const* d_in, const int* in_sizes, int n_in,
                              void* d_out, int out_size, void* d_ws, size_t ws_size,
                              hipStream_t stream) {
  const float* in   = (const float*)d_in[0];
  const float* wt   = (const float*)d_in[1];
  const float* bias = (const float*)d_in[2];
  float* out = (float*)d_out;
  hipLaunchKernelGGL(mvcnn_down, dim3(NB), dim3(1024), 0, stream,
                     in, wt, bias, out);
}